// Round 1
// baseline (413.430 us; speedup 1.0000x reference)
//
#include <hip/hip_runtime.h>
#include <hip/hip_bf16.h>

// Problem constants
#define B_    32
#define H_    64
#define W_    64
#define C_    256
#define NH_   8
#define N_    16
#define PIX_  (B_*H_*W_)     // 131072
#define OUTPIX_ (B_*32*32)   // 32768

typedef __hip_bfloat16 bf16;
typedef __attribute__((ext_vector_type(8))) short bf16x8;   // 8 bf16 = 4 VGPR
typedef __attribute__((ext_vector_type(4))) float f32x4;

__device__ __forceinline__ float bf2f(unsigned short u) {
  union { unsigned int i; float f; } v; v.i = ((unsigned int)u) << 16; return v.f;
}
__device__ __forceinline__ unsigned pk2(float a, float b) {
  union { __hip_bfloat162 h2; unsigned u; } c;
  c.h2 = __float22bfloat162_rn(make_float2(a, b));
  return c.u;
}
// 8 consecutive fp32 -> bf16x8 (same rounding as the old LDS staging path)
__device__ __forceinline__ bf16x8 cvt8(float4 lo, float4 hi) {
  union { bf16x8 v; unsigned u[4]; } r;
  r.u[0] = pk2(lo.x, lo.y); r.u[1] = pk2(lo.z, lo.w);
  r.u[2] = pk2(hi.x, hi.y); r.u[3] = pk2(hi.z, hi.w);
  return r.v;
}

// ---------------------------------------------------------------------------
// K1: s0[8][16] (softmax row 0 of logits) and qv[8]. One block.
// ---------------------------------------------------------------------------
__global__ __launch_bounds__(256) void k1_setup(
    const float* __restrict__ emb, const float* __restrict__ wkq_w,
    const float* __restrict__ wkq_b, const float* __restrict__ wgq_w,
    const float* __restrict__ wgq_b,
    float* __restrict__ s0, float* __restrict__ qv) {
  __shared__ float lq[128];
  __shared__ float lk[16][8];
  int t = threadIdx.x;
  if (t < 128) {
    float acc = wkq_b[128 + t];
    for (int e = 0; e < 128; ++e) acc += emb[e] * wkq_w[e * 256 + 128 + t];
    lq[t] = acc;
  } else {
    int idx = t - 128; int j = idx >> 3, h = idx & 7;
    float acc = wkq_b[h * 16];
    for (int e = 0; e < 128; ++e) acc += emb[j * 128 + e] * wkq_w[e * 256 + h * 16];
    lk[j][h] = acc;
  }
  __syncthreads();
  if (t < 8) {
    float l[16]; float m = -1e30f;
    for (int j = 0; j < 16; ++j) { l[j] = lq[t * 16 + j] + lk[j][t]; m = fmaxf(m, l[j]); }
    float s = 0.f;
    for (int j = 0; j < 16; ++j) { l[j] = expf(l[j] - m); s += l[j]; }
    float inv = 1.f / s;
    for (int j = 0; j < 16; ++j) s0[t * 16 + j] = l[j] * inv;
    float acc = wgq_b[t];
    for (int e = 0; e < 128; ++e) acc += emb[14 * 128 + e] * wgq_w[e * 8 + t];
    qv[t] = acc;
  }
}

// ---------------------------------------------------------------------------
// prep: LDS-tiled transposes to bf16.
//   blocks 0..15 : wvT[n][k]  = wv[k][n]   (64x64 tiles)
//   blocks 16..31: wfT[n][k]  = wf[k][n]
//   block  32    : wgkT[a][k] = wgk[k][a]  (rows 8..15 zero)
// ---------------------------------------------------------------------------
__global__ __launch_bounds__(256) void prep(
    const float* __restrict__ wv, const float* __restrict__ wf,
    const float* __restrict__ wgk,
    bf16* __restrict__ wvT, bf16* __restrict__ wfT, bf16* __restrict__ wgkT) {
  int bid = blockIdx.x, t = threadIdx.x;
  if (bid < 32) {
    __shared__ unsigned short tile[64][72];
    const float* src = (bid < 16) ? wv : wf;
    bf16* dst = (bid < 16) ? wvT : wfT;
    int tb = bid & 15, tr = tb >> 2, tc = tb & 3;
#pragma unroll
    for (int it = 0; it < 16; ++it) {
      int idx = it * 256 + t, row = idx >> 6, col = idx & 63;
      bf16 h = __float2bfloat16(src[(tr * 64 + row) * 256 + tc * 64 + col]);
      tile[row][col] = *(unsigned short*)&h;
    }
    __syncthreads();
#pragma unroll
    for (int it = 0; it < 16; ++it) {
      int idx = it * 256 + t, row = idx >> 6, col = idx & 63;
      dst[(tc * 64 + row) * 256 + (tr * 64 + col)] = *(bf16*)&tile[col][row];
    }
  } else {
    __shared__ float g[2048];
#pragma unroll
    for (int it = 0; it < 8; ++it) g[it * 256 + t] = wgk[it * 256 + t];
    __syncthreads();
#pragma unroll
    for (int it = 0; it < 16; ++it) {
      int idx = it * 256 + t, a = idx >> 8, k = idx & 255;
      float v = (a < 8) ? g[k * 8 + a] : 0.f;
      wgkT[a * 256 + k] = __float2bfloat16(v);
    }
  }
}

// ---------------------------------------------------------------------------
// kA v2 (barrier-free streaming GEMM + fused gate):
//   vraw = inps @ wv + wv_b          (bf16 out, no scale yet)
//   g    = relu(qv + inps @ wgk + b) -> gbuf; denom += sum(g)
// No LDS staging: each wave streams its A fragments straight from inps
// (float4 pairs, fp32->bf16 cvt in-register; A re-read 4x across nw waves
// is served by per-XCD L2). No block barrier in the main loop -> no
// vmcnt(0)+s_barrier drain; waves pipeline loads independently.
// 512 thr = 8 waves, wave tile M32xN64. Gate rides nw==0 waves.
// ---------------------------------------------------------------------------
__global__ __launch_bounds__(512, 4) void kA(
    const float* __restrict__ inps, const bf16* __restrict__ wvT,
    const bf16* __restrict__ wgkT, const float* __restrict__ wv_b,
    const float* __restrict__ wgk_b, const float* __restrict__ qv,
    bf16* __restrict__ vraw, float* __restrict__ gbuf,
    float* __restrict__ denom) {
  __shared__ float sden[8];
  __shared__ float qvb_s[8];
  int t = threadIdx.x;
  long pix0 = (long)blockIdx.x * 64;
  if (t < 8) { sden[t] = 0.f; qvb_s[t] = qv[t] + wgk_b[t]; }
  __syncthreads();   // only guards the tiny sden/qvb_s init (no loads pending)

  int wave = t >> 6, lane = t & 63;
  int mw = wave >> 2, nw = wave & 3;
  int m0 = mw * 32, n0 = nw * 64;
  int lm = lane & 15, q = lane >> 4;
  bool gatew = (nw == 0);

  f32x4 acc[2][4], accg[2];
#pragma unroll
  for (int mf = 0; mf < 2; ++mf) {
    accg[mf] = (f32x4){0.f, 0.f, 0.f, 0.f};
#pragma unroll
    for (int nf = 0; nf < 4; ++nf) acc[mf][nf] = (f32x4){0.f, 0.f, 0.f, 0.f};
  }
  // A rows for this lane (fp32, 64 float4 per row)
  const float4* ar0 = (const float4*)(inps + (pix0 + m0 + lm) * 256);
  const float4* ar1 = (const float4*)(inps + (pix0 + m0 + 16 + lm) * 256);
  const bf16* brow = wvT + (n0 + lm) * 256;
  const bf16* grow = wgkT + lm * 256;

#pragma unroll
  for (int ks = 0; ks < 8; ++ks) {
    int i0 = ks * 8 + q * 2;                 // float4 index within row
    float4 a0lo = ar0[i0], a0hi = ar0[i0 + 1];
    float4 a1lo = ar1[i0], a1hi = ar1[i0 + 1];
    int kof = ks * 32 + q * 8;
    bf16x8 b0 = *(const bf16x8*)(brow + kof);
    bf16x8 b1 = *(const bf16x8*)(brow + 4096 + kof);
    bf16x8 b2 = *(const bf16x8*)(brow + 8192 + kof);
    bf16x8 b3 = *(const bf16x8*)(brow + 12288 + kof);
    bf16x8 a0 = cvt8(a0lo, a0hi);
    bf16x8 a1 = cvt8(a1lo, a1hi);
    acc[0][0] = __builtin_amdgcn_mfma_f32_16x16x32_bf16(a0, b0, acc[0][0], 0, 0, 0);
    acc[1][0] = __builtin_amdgcn_mfma_f32_16x16x32_bf16(a1, b0, acc[1][0], 0, 0, 0);
    acc[0][1] = __builtin_amdgcn_mfma_f32_16x16x32_bf16(a0, b1, acc[0][1], 0, 0, 0);
    acc[1][1] = __builtin_amdgcn_mfma_f32_16x16x32_bf16(a1, b1, acc[1][1], 0, 0, 0);
    acc[0][2] = __builtin_amdgcn_mfma_f32_16x16x32_bf16(a0, b2, acc[0][2], 0, 0, 0);
    acc[1][2] = __builtin_amdgcn_mfma_f32_16x16x32_bf16(a1, b2, acc[1][2], 0, 0, 0);
    acc[0][3] = __builtin_amdgcn_mfma_f32_16x16x32_bf16(a0, b3, acc[0][3], 0, 0, 0);
    acc[1][3] = __builtin_amdgcn_mfma_f32_16x16x32_bf16(a1, b3, acc[1][3], 0, 0, 0);
    if (gatew) {
      bf16x8 bg = *(const bf16x8*)(grow + kof);
      accg[0] = __builtin_amdgcn_mfma_f32_16x16x32_bf16(a0, bg, accg[0], 0, 0, 0);
      accg[1] = __builtin_amdgcn_mfma_f32_16x16x32_bf16(a1, bg, accg[1], 0, 0, 0);
    }
  }

  // vraw epilogue (bias only; scale applied in kB)
#pragma unroll
  for (int nf = 0; nf < 4; ++nf) {
    int col = n0 + nf * 16 + lm;
    float wb = wv_b[col];
#pragma unroll
    for (int mf = 0; mf < 2; ++mf) {
#pragma unroll
      for (int r = 0; r < 4; ++r) {
        int rl = m0 + mf * 16 + q * 4 + r;
        vraw[(pix0 + rl) * 256 + col] = __float2bfloat16(acc[mf][nf][r] + wb);
      }
    }
  }

  // gate epilogue
  if (gatew) {
    float part = 0.f;
    if (lm < 8) {
#pragma unroll
      for (int mf = 0; mf < 2; ++mf) {
#pragma unroll
        for (int r = 0; r < 4; ++r) {
          int rl = m0 + mf * 16 + q * 4 + r;
          float gg = fmaxf(qvb_s[lm] + accg[mf][r], 0.f);
          gbuf[(pix0 + rl) * 8 + lm] = gg;
          part += gg;
        }
      }
    }
    part += __shfl_xor(part, 16, 64);
    part += __shfl_xor(part, 32, 64);
    if (lane < 16 && lm < 8) atomicAdd(&sden[lm], part);
  }
  __syncthreads();
  if (t < 8) atomicAdd(&denom[(int)(pix0 >> 12) * 8 + t], sden[t]);
}

// ---------------------------------------------------------------------------
// kB (fused scale + patch gather + final GEMM). Block = (b,x) row, 256 thr.
// Phase 0: stage scf[i][c][a] = 4096/(denom+eps)*g for the 4 source rows.
// Phase 1: op[y][ch] = sum_taps (s0*scf) * vraw   (uint = 2ch per lane)
// Phase 2: out = op @ wf + wf_b via MFMA (wfT in L2).
// ---------------------------------------------------------------------------
__global__ __launch_bounds__(256) void kB(
    const bf16* __restrict__ vraw, const float* __restrict__ s0,
    const float* __restrict__ gbuf, const float* __restrict__ denom,
    const bf16* __restrict__ wfT, const float* __restrict__ wf_b,
    float* __restrict__ out) {
  __shared__ float scfsh[4][64][8];                      // 8 KB
  __shared__ __align__(16) unsigned short opsh[32][264]; // bf16 bits
  int t = threadIdx.x;
  int bx = blockIdx.x, b = bx >> 5, x = bx & 31;

  { // phase 0
    int i = t >> 6, c = t & 63;
    int r = 2 * x + i - 1;
    if (r >= 0 && r < 64) {
      long p = (long)b * 4096 + r * 64 + c;
#pragma unroll
      for (int a = 0; a < 8; ++a)
        scfsh[i][c][a] = 4096.0f / (denom[b * 8 + a] + 1e-6f) * gbuf[p * 8 + a];
    } else {
#pragma unroll
      for (int a = 0; a < 8; ++a) scfsh[i][c][a] = 0.f;
    }
  }
  __syncthreads();

  // phase 1
  int c2 = t & 127, yg = t >> 7;
  int h = c2 >> 4;
  float s0r[16];
#pragma unroll
  for (int n = 0; n < 16; ++n) s0r[n] = s0[h * 16 + n];
  const bf16* vsb = vraw + (long)b * (4096 * 256);
  for (int yi = 0; yi < 16; ++yi) {
    int y = yi * 2 + yg;
    float p0 = 0.f, p1 = 0.f;
#pragma unroll
    for (int i = 0; i < 4; ++i) {
      int r = 2 * x + i - 1;
      if (r < 0 || r >= 64) continue;               // block-uniform
      const bf16* rowp = vsb + (long)r * 64 * 256 + 2 * c2;
#pragma unroll
      for (int j = 0; j < 4; ++j) {
        int c = 2 * y + j - 1;
        if (c < 0 || c >= 64) continue;             // wave-uniform
        float coef = s0r[i * 4 + j] * scfsh[i][c][h];
        unsigned u = *(const unsigned*)(rowp + (long)c * 256);
        p0 += coef * bf2f((unsigned short)(u & 0xffff));
        p1 += coef * bf2f((unsigned short)(u >> 16));
      }
    }
    *(unsigned*)&opsh[y][2 * c2] = pk2(p0, p1);
  }
  __syncthreads();

  // phase 2: MFMA  out[32x256] = op @ wf + b
  int wave = t >> 6, lane = t & 63;
  int n0 = wave * 64;
  int lm = lane & 15, q = lane >> 4;
  f32x4 acc[2][4];
#pragma unroll
  for (int mf = 0; mf < 2; ++mf)
#pragma unroll
    for (int nf = 0; nf < 4; ++nf) acc[mf][nf] = (f32x4){0.f, 0.f, 0.f, 0.f};
  const bf16* brow = wfT + (n0 + lm) * 256;
#pragma unroll
  for (int ks = 0; ks < 8; ++ks) {
    int kof = ks * 32 + q * 8;
    bf16x8 a0 = *(const bf16x8*)(&opsh[lm][kof]);
    bf16x8 a1 = *(const bf16x8*)(&opsh[16 + lm][kof]);
#pragma unroll
    for (int nf = 0; nf < 4; ++nf) {
      bf16x8 bb = *(const bf16x8*)(brow + nf * 4096 + kof);
      acc[0][nf] = __builtin_amdgcn_mfma_f32_16x16x32_bf16(a0, bb, acc[0][nf], 0, 0, 0);
      acc[1][nf] = __builtin_amdgcn_mfma_f32_16x16x32_bf16(a1, bb, acc[1][nf], 0, 0, 0);
    }
  }
  long out0 = (long)bx * 32 * 256;
#pragma unroll
  for (int nf = 0; nf < 4; ++nf) {
    int col = n0 + nf * 16 + lm;
    float wb = wf_b[col];
#pragma unroll
    for (int mf = 0; mf < 2; ++mf) {
#pragma unroll
      for (int r = 0; r < 4; ++r) {
        int row = mf * 16 + q * 4 + r;
        out[out0 + row * 256 + col] = acc[mf][nf][r] + wb;
      }
    }
  }
}

// ---------------------------------------------------------------------------
// Workspace (float offsets): s0 0 | qv 128 | denom 256 | gbuf 1024 (+1M)
// wvT @1049600 (+32768) | wfT @1082368 (+32768) | wgkT @1115136 (+2048)
// vraw(bf16) @1117184 (+16.7M f-equiv). Total ~71.6 MB.
// ---------------------------------------------------------------------------
extern "C" void kernel_launch(void* const* d_in, const int* in_sizes, int n_in,
                              void* d_out, int out_size, void* d_ws, size_t ws_size,
                              hipStream_t stream) {
  const float* inps  = (const float*)d_in[0];
  const float* emb   = (const float*)d_in[1];
  const float* wkq_w = (const float*)d_in[2];
  const float* wkq_b = (const float*)d_in[3];
  const float* wv_w  = (const float*)d_in[4];
  const float* wv_b  = (const float*)d_in[5];
  const float* wgq_w = (const float*)d_in[6];
  const float* wgq_b = (const float*)d_in[7];
  const float* wgk_w = (const float*)d_in[8];
  const float* wgk_b = (const float*)d_in[9];
  const float* wf_w  = (const float*)d_in[10];
  const float* wf_b  = (const float*)d_in[11];

  float* wsf   = (float*)d_ws;
  float* s0f   = wsf;
  float* qvf   = wsf + 128;
  float* denom = wsf + 256;
  float* gbuf  = wsf + 1024;
  bf16*  wvT   = (bf16*)(wsf + 1049600);
  bf16*  wfT   = (bf16*)(wsf + 1082368);
  bf16*  wgkT  = (bf16*)(wsf + 1115136);
  bf16*  vraw  = (bf16*)(wsf + 1117184);
  float* outp  = (float*)d_out;

  hipMemsetAsync((void*)denom, 0, 1024, stream);
  k1_setup<<<1, 256, 0, stream>>>(emb, wkq_w, wkq_b, wgq_w, wgq_b, s0f, qvf);
  prep<<<33, 256, 0, stream>>>(wv_w, wf_w, wgk_w, wvT, wfT, wgkT);
  kA<<<PIX_ / 64, 512, 0, stream>>>(inps, wvT, wgkT, wv_b, wgk_b, qvf,
                                    vraw, gbuf, denom);
  kB<<<OUTPIX_ / 32, 256, 0, stream>>>(vraw, s0f, gbuf, denom, wfT, wf_b, outp);
}

// Round 2
// 406.420 us; speedup vs baseline: 1.0172x; 1.0172x over previous
//
#include <hip/hip_runtime.h>
#include <hip/hip_bf16.h>

// Problem constants
#define B_    32
#define H_    64
#define W_    64
#define C_    256
#define NH_   8
#define N_    16
#define PIX_  (B_*H_*W_)     // 131072
#define OUTPIX_ (B_*32*32)   // 32768

typedef __hip_bfloat16 bf16;
typedef __attribute__((ext_vector_type(8))) short bf16x8;   // 8 bf16 = 4 VGPR
typedef __attribute__((ext_vector_type(4))) float f32x4;

__device__ __forceinline__ float bf2f(unsigned short u) {
  union { unsigned int i; float f; } v; v.i = ((unsigned int)u) << 16; return v.f;
}
__device__ __forceinline__ unsigned pk2(float a, float b) {
  union { __hip_bfloat162 h2; unsigned u; } c;
  c.h2 = __float22bfloat162_rn(make_float2(a, b));
  return c.u;
}

// ---------------------------------------------------------------------------
// K1: s0[8][16] (softmax row 0 of logits) and qv[8]. One block.
// ---------------------------------------------------------------------------
__global__ __launch_bounds__(256) void k1_setup(
    const float* __restrict__ emb, const float* __restrict__ wkq_w,
    const float* __restrict__ wkq_b, const float* __restrict__ wgq_w,
    const float* __restrict__ wgq_b,
    float* __restrict__ s0, float* __restrict__ qv) {
  __shared__ float lq[128];
  __shared__ float lk[16][8];
  int t = threadIdx.x;
  if (t < 128) {
    float acc = wkq_b[128 + t];
    for (int e = 0; e < 128; ++e) acc += emb[e] * wkq_w[e * 256 + 128 + t];
    lq[t] = acc;
  } else {
    int idx = t - 128; int j = idx >> 3, h = idx & 7;
    float acc = wkq_b[h * 16];
    for (int e = 0; e < 128; ++e) acc += emb[j * 128 + e] * wkq_w[e * 256 + h * 16];
    lk[j][h] = acc;
  }
  __syncthreads();
  if (t < 8) {
    float l[16]; float m = -1e30f;
    for (int j = 0; j < 16; ++j) { l[j] = lq[t * 16 + j] + lk[j][t]; m = fmaxf(m, l[j]); }
    float s = 0.f;
    for (int j = 0; j < 16; ++j) { l[j] = expf(l[j] - m); s += l[j]; }
    float inv = 1.f / s;
    for (int j = 0; j < 16; ++j) s0[t * 16 + j] = l[j] * inv;
    float acc = wgq_b[t];
    for (int e = 0; e < 128; ++e) acc += emb[14 * 128 + e] * wgq_w[e * 8 + t];
    qv[t] = acc;
  }
}

// ---------------------------------------------------------------------------
// prep: LDS-tiled transposes to bf16.
//   blocks 0..15 : wvT[n][k]  = wv[k][n]   (64x64 tiles)
//   blocks 16..31: wfT[n][k]  = wf[k][n]
//   block  32    : wgkT[a][k] = wgk[k][a]  (rows 8..15 zero)
// ---------------------------------------------------------------------------
__global__ __launch_bounds__(256) void prep(
    const float* __restrict__ wv, const float* __restrict__ wf,
    const float* __restrict__ wgk,
    bf16* __restrict__ wvT, bf16* __restrict__ wfT, bf16* __restrict__ wgkT) {
  int bid = blockIdx.x, t = threadIdx.x;
  if (bid < 32) {
    __shared__ unsigned short tile[64][72];
    const float* src = (bid < 16) ? wv : wf;
    bf16* dst = (bid < 16) ? wvT : wfT;
    int tb = bid & 15, tr = tb >> 2, tc = tb & 3;
#pragma unroll
    for (int it = 0; it < 16; ++it) {
      int idx = it * 256 + t, row = idx >> 6, col = idx & 63;
      bf16 h = __float2bfloat16(src[(tr * 64 + row) * 256 + tc * 64 + col]);
      tile[row][col] = *(unsigned short*)&h;
    }
    __syncthreads();
#pragma unroll
    for (int it = 0; it < 16; ++it) {
      int idx = it * 256 + t, row = idx >> 6, col = idx & 63;
      dst[(tc * 64 + row) * 256 + (tr * 64 + col)] = *(bf16*)&tile[col][row];
    }
  } else {
    __shared__ float g[2048];
#pragma unroll
    for (int it = 0; it < 8; ++it) g[it * 256 + t] = wgk[it * 256 + t];
    __syncthreads();
#pragma unroll
    for (int it = 0; it < 16; ++it) {
      int idx = it * 256 + t, a = idx >> 8, k = idx & 255;
      float v = (a < 8) ? g[k * 8 + a] : 0.f;
      wgkT[a * 256 + k] = __float2bfloat16(v);
    }
  }
}

// ---------------------------------------------------------------------------
// kA v3 (pipelined LDS-staged GEMM + fused gate):
//   vraw = inps @ wv + wv_b          (bf16 out, no scale yet)
//   g    = relu(qv + inps @ wgk + b) -> gbuf; denom += sum(g)
// Grid-stride: 512 blocks x 4 tiles of 64 px. A staged per half-K (64x128)
// into double-buffered LDS; register prefetch keeps one full half-tile of
// HBM loads (32 KB/block) in flight through every compute phase. One
// barrier per phase. Wave tile M32xN64 (8 waves). Gate rides nw==0 waves.
// ---------------------------------------------------------------------------
#define KA_TILES 4
__global__ __launch_bounds__(512, 4) void kA(
    const float* __restrict__ inps, const bf16* __restrict__ wvT,
    const bf16* __restrict__ wgkT, const float* __restrict__ wv_b,
    const float* __restrict__ wgk_b, const float* __restrict__ qv,
    bf16* __restrict__ vraw, float* __restrict__ gbuf,
    float* __restrict__ denom) {
  // [2 buffers][64 rows][128 bf16 + 8 pad] = 34816 B
  __shared__ __align__(16) unsigned short ldsA[2][64][136];
  __shared__ float sden[8];
  __shared__ float qvb_s[8];
  int t = threadIdx.x;
  int bid = blockIdx.x;
  const long px_base = (long)bid * (KA_TILES * 64);
  if (t < 8) { sden[t] = 0.f; qvb_s[t] = qv[t] + wgk_b[t]; }

  int wave = t >> 6, lane = t & 63;
  int mw = wave >> 2, nw = wave & 3;
  int m0 = mw * 32, n0 = nw * 64;
  int lm = lane & 15, q = lane >> 4;
  bool gatew = (nw == 0);
  const bf16* brow = wvT + (n0 + lm) * 256;
  const bf16* grow = wgkT + lm * 256;

  // staging: thread t handles rows {sr, sr+16, sr+32, sr+48}, col4 sc4 of a
  // 64x128 half-tile (4 float4 = 16 floats per thread per phase).
  int sr = t >> 5, sc4 = t & 31;
  const float* sbase = inps + px_base * 256 + sr * 256 + sc4 * 4;
  float4 st[4];

  // phase ph (0..7): tile ph>>1, K-half ph&1
#define LOADST(ph_)                                                          \
  {                                                                          \
    const float* s_ = sbase + ((ph_) >> 1) * (64 * 256) + ((ph_) & 1) * 128; \
    _Pragma("unroll")                                                        \
    for (int it = 0; it < 4; ++it)                                           \
      st[it] = *(const float4*)(s_ + it * 16 * 256);                         \
  }
#define WRITEST(bufi_)                                                       \
  {                                                                          \
    _Pragma("unroll")                                                        \
    for (int it = 0; it < 4; ++it)                                           \
      *(uint2*)&ldsA[bufi_][it * 16 + sr][sc4 * 4] =                         \
          make_uint2(pk2(st[it].x, st[it].y), pk2(st[it].z, st[it].w));      \
  }

  LOADST(0);
  WRITEST(0);
  LOADST(1);              // in flight across phase 0's compute
  __syncthreads();

  f32x4 acc[2][4], accg[2];
  float gsum = 0.f;

#pragma unroll 2
  for (int ph = 0; ph < 2 * KA_TILES; ++ph) {
    const int cur = ph & 1;
    if (cur == 0) {
#pragma unroll
      for (int mf = 0; mf < 2; ++mf) {
        accg[mf] = (f32x4){0.f, 0.f, 0.f, 0.f};
#pragma unroll
        for (int nf = 0; nf < 4; ++nf) acc[mf][nf] = (f32x4){0.f, 0.f, 0.f, 0.f};
      }
    }
    // compute this half (K 0..127 or 128..255 of the tile)
    const unsigned short* arow0 = &ldsA[cur][m0 + lm][0];
    const unsigned short* arow1 = &ldsA[cur][m0 + 16 + lm][0];
#pragma unroll
    for (int ksl = 0; ksl < 4; ++ksl) {
      int kof = ksl * 32 + q * 8;
      bf16x8 a0 = *(const bf16x8*)(arow0 + kof);
      bf16x8 a1 = *(const bf16x8*)(arow1 + kof);
      int gk = cur * 128 + kof;
      bf16x8 b0 = *(const bf16x8*)(brow + gk);
      bf16x8 b1 = *(const bf16x8*)(brow + 4096 + gk);
      bf16x8 b2 = *(const bf16x8*)(brow + 8192 + gk);
      bf16x8 b3 = *(const bf16x8*)(brow + 12288 + gk);
      acc[0][0] = __builtin_amdgcn_mfma_f32_16x16x32_bf16(a0, b0, acc[0][0], 0, 0, 0);
      acc[1][0] = __builtin_amdgcn_mfma_f32_16x16x32_bf16(a1, b0, acc[1][0], 0, 0, 0);
      acc[0][1] = __builtin_amdgcn_mfma_f32_16x16x32_bf16(a0, b1, acc[0][1], 0, 0, 0);
      acc[1][1] = __builtin_amdgcn_mfma_f32_16x16x32_bf16(a1, b1, acc[1][1], 0, 0, 0);
      acc[0][2] = __builtin_amdgcn_mfma_f32_16x16x32_bf16(a0, b2, acc[0][2], 0, 0, 0);
      acc[1][2] = __builtin_amdgcn_mfma_f32_16x16x32_bf16(a1, b2, acc[1][2], 0, 0, 0);
      acc[0][3] = __builtin_amdgcn_mfma_f32_16x16x32_bf16(a0, b3, acc[0][3], 0, 0, 0);
      acc[1][3] = __builtin_amdgcn_mfma_f32_16x16x32_bf16(a1, b3, acc[1][3], 0, 0, 0);
      if (gatew) {
        bf16x8 bg = *(const bf16x8*)(grow + gk);
        accg[0] = __builtin_amdgcn_mfma_f32_16x16x32_bf16(a0, bg, accg[0], 0, 0, 0);
        accg[1] = __builtin_amdgcn_mfma_f32_16x16x32_bf16(a1, bg, accg[1], 0, 0, 0);
      }
    }

    if (cur == 1) {  // tile complete: epilogues
      long pix0 = px_base + (ph >> 1) * 64;
      // vraw (bias only; scale applied in kB)
#pragma unroll
      for (int nf = 0; nf < 4; ++nf) {
        int col = n0 + nf * 16 + lm;
        float wb = wv_b[col];
#pragma unroll
        for (int mf = 0; mf < 2; ++mf) {
#pragma unroll
          for (int r = 0; r < 4; ++r) {
            int rl = m0 + mf * 16 + q * 4 + r;
            vraw[(pix0 + rl) * 256 + col] = __float2bfloat16(acc[mf][nf][r] + wb);
          }
        }
      }
      // gate: store g, accumulate per-lane partial sum across tiles
      if (gatew && lm < 8) {
#pragma unroll
        for (int mf = 0; mf < 2; ++mf) {
#pragma unroll
          for (int r = 0; r < 4; ++r) {
            int rl = m0 + mf * 16 + q * 4 + r;
            float gg = fmaxf(qvb_s[lm] + accg[mf][r], 0.f);
            gbuf[(pix0 + rl) * 8 + lm] = gg;
            gsum += gg;
          }
        }
      }
    }

    // pipeline tail: write prefetched half (ph+1) to its buffer, then issue
    // loads for ph+2 so a full half-tile stays in flight over next compute.
    if (ph < 2 * KA_TILES - 1) {
      WRITEST(cur ^ 1);
      if (ph < 2 * KA_TILES - 2) LOADST(ph + 2);
    }
    __syncthreads();
  }

  // gate reduction: one LDS atomic per gate wave, one global atomic per block
  if (gatew) {
    gsum += __shfl_xor(gsum, 16, 64);
    gsum += __shfl_xor(gsum, 32, 64);
    if (lane < 8) atomicAdd(&sden[lane], gsum);
  }
  __syncthreads();
  if (t < 8) atomicAdd(&denom[(bid >> 4) * 8 + t], sden[t]);
#undef LOADST
#undef WRITEST
}

// ---------------------------------------------------------------------------
// kB (fused scale + patch gather + final GEMM). Block = (b,x) row, 256 thr.
// Phase 0: stage scf[i][c][a] = 4096/(denom+eps)*g for the 4 source rows.
// Phase 1: op[y][ch] = sum_taps (s0*scf) * vraw   (uint = 2ch per lane)
// Phase 2: out = op @ wf + wf_b via MFMA (wfT in L2).
// ---------------------------------------------------------------------------
__global__ __launch_bounds__(256) void kB(
    const bf16* __restrict__ vraw, const float* __restrict__ s0,
    const float* __restrict__ gbuf, const float* __restrict__ denom,
    const bf16* __restrict__ wfT, const float* __restrict__ wf_b,
    float* __restrict__ out) {
  __shared__ float scfsh[4][64][8];                      // 8 KB
  __shared__ __align__(16) unsigned short opsh[32][264]; // bf16 bits
  int t = threadIdx.x;
  int bx = blockIdx.x, b = bx >> 5, x = bx & 31;

  { // phase 0
    int i = t >> 6, c = t & 63;
    int r = 2 * x + i - 1;
    if (r >= 0 && r < 64) {
      long p = (long)b * 4096 + r * 64 + c;
#pragma unroll
      for (int a = 0; a < 8; ++a)
        scfsh[i][c][a] = 4096.0f / (denom[b * 8 + a] + 1e-6f) * gbuf[p * 8 + a];
    } else {
#pragma unroll
      for (int a = 0; a < 8; ++a) scfsh[i][c][a] = 0.f;
    }
  }
  __syncthreads();

  // phase 1
  int c2 = t & 127, yg = t >> 7;
  int h = c2 >> 4;
  float s0r[16];
#pragma unroll
  for (int n = 0; n < 16; ++n) s0r[n] = s0[h * 16 + n];
  const bf16* vsb = vraw + (long)b * (4096 * 256);
  for (int yi = 0; yi < 16; ++yi) {
    int y = yi * 2 + yg;
    float p0 = 0.f, p1 = 0.f;
#pragma unroll
    for (int i = 0; i < 4; ++i) {
      int r = 2 * x + i - 1;
      if (r < 0 || r >= 64) continue;               // block-uniform
      const bf16* rowp = vsb + (long)r * 64 * 256 + 2 * c2;
#pragma unroll
      for (int j = 0; j < 4; ++j) {
        int c = 2 * y + j - 1;
        if (c < 0 || c >= 64) continue;             // wave-uniform
        float coef = s0r[i * 4 + j] * scfsh[i][c][h];
        unsigned u = *(const unsigned*)(rowp + (long)c * 256);
        p0 += coef * bf2f((unsigned short)(u & 0xffff));
        p1 += coef * bf2f((unsigned short)(u >> 16));
      }
    }
    *(unsigned*)&opsh[y][2 * c2] = pk2(p0, p1);
  }
  __syncthreads();

  // phase 2: MFMA  out[32x256] = op @ wf + b
  int wave = t >> 6, lane = t & 63;
  int n0 = wave * 64;
  int lm = lane & 15, q = lane >> 4;
  f32x4 acc[2][4];
#pragma unroll
  for (int mf = 0; mf < 2; ++mf)
#pragma unroll
    for (int nf = 0; nf < 4; ++nf) acc[mf][nf] = (f32x4){0.f, 0.f, 0.f, 0.f};
  const bf16* brow = wfT + (n0 + lm) * 256;
#pragma unroll
  for (int ks = 0; ks < 8; ++ks) {
    int kof = ks * 32 + q * 8;
    bf16x8 a0 = *(const bf16x8*)(&opsh[lm][kof]);
    bf16x8 a1 = *(const bf16x8*)(&opsh[16 + lm][kof]);
#pragma unroll
    for (int nf = 0; nf < 4; ++nf) {
      bf16x8 bb = *(const bf16x8*)(brow + nf * 4096 + kof);
      acc[0][nf] = __builtin_amdgcn_mfma_f32_16x16x32_bf16(a0, bb, acc[0][nf], 0, 0, 0);
      acc[1][nf] = __builtin_amdgcn_mfma_f32_16x16x32_bf16(a1, bb, acc[1][nf], 0, 0, 0);
    }
  }
  long out0 = (long)bx * 32 * 256;
#pragma unroll
  for (int nf = 0; nf < 4; ++nf) {
    int col = n0 + nf * 16 + lm;
    float wb = wf_b[col];
#pragma unroll
    for (int mf = 0; mf < 2; ++mf) {
#pragma unroll
      for (int r = 0; r < 4; ++r) {
        int row = mf * 16 + q * 4 + r;
        out[out0 + row * 256 + col] = acc[mf][nf][r] + wb;
      }
    }
  }
}

// ---------------------------------------------------------------------------
// Workspace (float offsets): s0 0 | qv 128 | denom 256 | gbuf 1024 (+1M)
// wvT @1049600 (+32768) | wfT @1082368 (+32768) | wgkT @1115136 (+2048)
// vraw(bf16) @1117184 (+16.7M f-equiv). Total ~71.6 MB.
// ---------------------------------------------------------------------------
extern "C" void kernel_launch(void* const* d_in, const int* in_sizes, int n_in,
                              void* d_out, int out_size, void* d_ws, size_t ws_size,
                              hipStream_t stream) {
  const float* inps  = (const float*)d_in[0];
  const float* emb   = (const float*)d_in[1];
  const float* wkq_w = (const float*)d_in[2];
  const float* wkq_b = (const float*)d_in[3];
  const float* wv_w  = (const float*)d_in[4];
  const float* wv_b  = (const float*)d_in[5];
  const float* wgq_w = (const float*)d_in[6];
  const float* wgq_b = (const float*)d_in[7];
  const float* wgk_w = (const float*)d_in[8];
  const float* wgk_b = (const float*)d_in[9];
  const float* wf_w  = (const float*)d_in[10];
  const float* wf_b  = (const float*)d_in[11];

  float* wsf   = (float*)d_ws;
  float* s0f   = wsf;
  float* qvf   = wsf + 128;
  float* denom = wsf + 256;
  float* gbuf  = wsf + 1024;
  bf16*  wvT   = (bf16*)(wsf + 1049600);
  bf16*  wfT   = (bf16*)(wsf + 1082368);
  bf16*  wgkT  = (bf16*)(wsf + 1115136);
  bf16*  vraw  = (bf16*)(wsf + 1117184);
  float* outp  = (float*)d_out;

  hipMemsetAsync((void*)denom, 0, 1024, stream);
  k1_setup<<<1, 256, 0, stream>>>(emb, wkq_w, wkq_b, wgq_w, wgq_b, s0f, qvf);
  prep<<<33, 256, 0, stream>>>(wv_w, wf_w, wgk_w, wvT, wfT, wgkT);
  kA<<<PIX_ / (KA_TILES * 64), 512, 0, stream>>>(inps, wvT, wgkT, wv_b, wgk_b, qvf,
                                                 vraw, gbuf, denom);
  kB<<<OUTPIX_ / 32, 256, 0, stream>>>(vraw, s0f, gbuf, denom, wfT, wf_b, outp);
}